// Round 1
// baseline (1070.932 us; speedup 1.0000x reference)
//
#include <hip/hip_runtime.h>
#include <hip/hip_bf16.h>
#include <hip/hip_fp16.h>

// GCN: h1 = relu(GCNConv(x,W1,b1)); h2 = GCNConv(h1,W2,b2);
//      h3 = relu(h2@Wm1+bm1); out = h3@Wm2+bm2
// R2: CSR-by-dst gather-reduce replaced scatter atomics (10x write amp).
// R4: 2-pass XCD-local bucket sort. R5: dinv folded into GEMM epilogue.
// R6/R8 FAILED: multi-phase LDS GEMM fusion -> spills. R7: fp16 g-tables.
// R9: 2-node/wave gather aggregate (255.8us). R13 FAILED: pad-4/4-wide
//      (latency-bound; needs 8-deep pipeline). R14: cleanup (253.7us).
// R15: scatter-side LDS aggregation. One block per 128-node dst bucket,
//      [128][64] fp32 accumulator in LDS (32KB), stream UNSORTED bucket
//      edge words, gather g[src] row (half-wave, 128B), ds_add_f32
//      accumulate (fire-and-forget; no recurrence, no per-node loop).
//      Kills: csr counting sort (replaced by trivial deg histogram),
//      pad-gather amp (1.4M->1.0M gathers), max(trip0,trip1) divergence,
//      colA write+reads. g stored feature-permuted (slot s = feats
//      (s, s+32)) so ds_add lanes hit banks 0-31 once per half-wave
//      (2-way = free). Word->gather chain broken by 1-batch-ahead word
//      prefetch; 8 gathers in flight per half-wave (R9-proven depth).

namespace {

constexpr int N_NODES = 100000;
constexpr int N_EDGES = 1000000;
constexpr int BN = 128;                         // dst nodes per bucket
constexpr int NBUCK = (N_NODES + BN - 1) / BN;  // 782 buckets
constexpr int CAP = 2048;    // edges/bucket: mean 1280, sd ~36 -> +21 sd
constexpr int EPB_A = 2048;  // edges per passA block

// passA: partition edges into NBUCK buckets by dst>>7. word=(src<<7)|(dst&127)
// (17+7=24 bits). Per-block int32/int64 detection: sample 512 odd words of own
// range (int64 high halves are all 0; int32 node ids ~surely not).
__global__ __launch_bounds__(256) void bucket_kernel(const void* __restrict__ ei,
                                                     int* __restrict__ bucketCnt,
                                                     unsigned* __restrict__ tmp) {
  __shared__ int hist[NBUCK];
  __shared__ int basePB[NBUCK];
  __shared__ int cur[NBUCK];
  __shared__ int sflag;
  int t = threadIdx.x;
  for (int i = t; i < NBUCK; i += 256) { hist[i] = 0; cur[i] = 0; }
  if (t == 0) sflag = 0;
  __syncthreads();

  int e0 = blockIdx.x * EPB_A;
  const unsigned* w = (const unsigned*)ei;
  unsigned any = 0;
#pragma unroll
  for (int s = 0; s < 2; s++) {
    int e = e0 + s * 256 + t;
    if (e < N_EDGES) any |= w[2 * e + 1];
  }
  if (any) sflag = 1;  // benign race, all writers store 1
  __syncthreads();
  int is32 = sflag;

  unsigned wreg[8];
  int breg[8];
#pragma unroll
  for (int k = 0; k < 8; k++) {
    int e = e0 + k * 256 + t;
    breg[k] = -1;
    if (e < N_EDGES) {
      int s, d;
      if (is32) {
        const int* p = (const int*)ei;
        s = p[e]; d = p[N_EDGES + e];
      } else {
        const long long* p = (const long long*)ei;
        s = (int)p[e]; d = (int)p[N_EDGES + e];
      }
      wreg[k] = ((unsigned)s << 7) | (unsigned)(d & 127);
      breg[k] = d >> 7;
      atomicAdd(&hist[breg[k]], 1);
    }
  }
  __syncthreads();
  for (int i = t; i < NBUCK; i += 256)
    basePB[i] = hist[i] ? atomicAdd(&bucketCnt[i], hist[i]) : 0;
  __syncthreads();
#pragma unroll
  for (int k = 0; k < 8; k++) {
    if (breg[k] >= 0) {
      int r = atomicAdd(&cur[breg[k]], 1);
      tmp[(size_t)breg[k] * CAP + basePB[breg[k]] + r] = wreg[k];
    }
  }
}

// deg: one block per bucket, LDS histogram of dstLow -> dinv. Replaces the
// whole csr counting-sort kernel (aggregation no longer needs sorted edges).
__global__ __launch_bounds__(256) void deg_kernel(const unsigned* __restrict__ tmp,
                                                  const int* __restrict__ bucketCnt,
                                                  float* __restrict__ dinv) {
  __shared__ int hist[BN];
  int b = blockIdx.x, t = threadIdx.x;
  if (t < BN) hist[t] = 0;
  __syncthreads();
  int cnt = bucketCnt[b];
  size_t base = (size_t)b * CAP;
  for (int i = t; i < cnt; i += 256) atomicAdd(&hist[tmp[base + i] & 127u], 1);
  __syncthreads();
  int d = b * BN + t;
  if (t < BN && d < N_NODES) dinv[d] = rsqrtf((float)hist[t] + 1.0f);
}

// g[r] = (op(A[r])@W) * dinv[r], fp16 out, FEATURE-PERMUTED: half2 slot s
// holds (feat s, feat s+32) -> gather half2 feeds conflict-free ds_add pairs.
// 128 rows/block, 256 thr, thread = 4 rows x cols {s0..s0+3, s0+32..s0+35}.
__global__ __launch_bounds__(256) void gemm_g_kernel(const float* __restrict__ A,
                                                     const float* __restrict__ W,
                                                     const float* __restrict__ dinv,
                                                     __half* __restrict__ g,
                                                     int reluIn) {
  __shared__ float Ws[64 * 64];
  int t = threadIdx.x;
  for (int i = t; i < 64 * 64 / 4; i += 256) ((float4*)Ws)[i] = ((const float4*)W)[i];
  __syncthreads();

  int rg = t >> 3, cg = t & 7;
  int r0 = blockIdx.x * 128 + rg * 4;
  int s0 = cg * 4;  // slot base: cols s0..s0+3 (j=0..3) and s0+32..s0+35 (j=4..7)

  float acc[4][8];
#pragma unroll
  for (int i = 0; i < 4; i++)
#pragma unroll
    for (int j = 0; j < 8; j++) acc[i][j] = 0.f;

  const float4* A4 = (const float4*)A;
  for (int kk = 0; kk < 16; kk++) {
    float4 a[4];
#pragma unroll
    for (int i = 0; i < 4; i++) {
      int r = r0 + i;
      float4 v = (r < N_NODES) ? A4[(size_t)r * 16 + kk] : make_float4(0.f, 0.f, 0.f, 0.f);
      if (reluIn) {
        v.x = fmaxf(v.x, 0.f); v.y = fmaxf(v.y, 0.f);
        v.z = fmaxf(v.z, 0.f); v.w = fmaxf(v.w, 0.f);
      }
      a[i] = v;
    }
#pragma unroll
    for (int q = 0; q < 4; q++) {
      int k = kk * 4 + q;
      float w[8];
      *(float4*)&w[0] = *(const float4*)&Ws[k * 64 + s0];
      *(float4*)&w[4] = *(const float4*)&Ws[k * 64 + 32 + s0];
#pragma unroll
      for (int i = 0; i < 4; i++) {
        float av = q == 0 ? a[i].x : q == 1 ? a[i].y : q == 2 ? a[i].z : a[i].w;
#pragma unroll
        for (int j = 0; j < 8; j++) acc[i][j] = fmaf(av, w[j], acc[i][j]);
      }
    }
  }
#pragma unroll
  for (int i = 0; i < 4; i++) {
    int r = r0 + i;
    if (r < N_NODES) {
      float s = dinv[r];
#pragma unroll
      for (int j = 0; j < 8; j++) acc[i][j] *= s;
      __half2 h0 = __floats2half2_rn(acc[i][0], acc[i][4]);
      __half2 h1 = __floats2half2_rn(acc[i][1], acc[i][5]);
      __half2 h2 = __floats2half2_rn(acc[i][2], acc[i][6]);
      __half2 h3 = __floats2half2_rn(acc[i][3], acc[i][7]);
      uint4 u;
      u.x = *(unsigned*)&h0; u.y = *(unsigned*)&h1;
      u.z = *(unsigned*)&h2; u.w = *(unsigned*)&h3;
      *(uint4*)(g + (size_t)r * 64 + s0 * 2) = u;
    }
  }
}

// Scatter-side LDS aggregation: one block per 128-dst bucket. [128][64] fp32
// accumulator in LDS (32KB). 8 half-waves stream 8-edge batches of unsorted
// words; per edge: half-wave gathers g[src] row (128B, lane sub -> half2
// (feat sub, sub+32)) and ds_add_f32 into acc[dstLow][sub] / [dstLow][32+sub]
// (banks 0-31 once per half = 2-way = free). Words prefetched 1 batch ahead
// so the word->gather chain never serializes. Epilogue: out = dinv_d *
// (acc + g_d) + bias, fp32, coalesced 128B per half-wave.
__global__ __launch_bounds__(256) void aggregate_lds(const __half2* __restrict__ g2,
                                                     const unsigned* __restrict__ tmp,
                                                     const int* __restrict__ bucketCnt,
                                                     const float* __restrict__ dinv,
                                                     const float* __restrict__ bias,
                                                     float* __restrict__ out) {
  __shared__ float acc[BN * 64];  // 32KB
  int t = threadIdx.x;
  float4* a4 = (float4*)acc;
#pragma unroll
  for (int i = 0; i < 8; i++) a4[t + 256 * i] = make_float4(0.f, 0.f, 0.f, 0.f);
  __syncthreads();

  int b = blockIdx.x;
  int cnt = bucketCnt[b];
  size_t base = (size_t)b * CAP;
  int lane = t & 63, half = lane >> 5, sub = lane & 31;
  int hid = (t >> 6) * 2 + half;  // half-wave id 0..7

  int e0 = hid * 8;
  uint4 wa, wb;
  if (e0 < cnt) {
    wa = *(const uint4*)(tmp + base + e0);
    wb = *(const uint4*)(tmp + base + e0 + 4);
  }
  for (; e0 < cnt; e0 += 64) {
    // prefetch next batch's words (unguarded; tmp has tail slack, masked by rem)
    uint4 na = *(const uint4*)(tmp + base + e0 + 64);
    uint4 nb = *(const uint4*)(tmp + base + e0 + 68);
    int rem = cnt - e0;
    unsigned ws8[8] = {wa.x, wa.y, wa.z, wa.w, wb.x, wb.y, wb.z, wb.w};
    float2 v[8];
    int dr[8];
#pragma unroll
    for (int k = 0; k < 8; k++) {
      if (k < rem) {
        unsigned w = ws8[k];
        dr[k] = w & 127;
        v[k] = __half22float2(g2[(size_t)(w >> 7) * 32 + sub]);
      }
    }
#pragma unroll
    for (int k = 0; k < 8; k++) {
      if (k < rem) {
        atomicAdd(&acc[dr[k] * 64 + sub], v[k].x);
        atomicAdd(&acc[dr[k] * 64 + 32 + sub], v[k].y);
      }
    }
    wa = na; wb = nb;
  }
  __syncthreads();

  float b0 = bias[sub], b1 = bias[sub + 32];
  for (int r = hid; r < BN; r += 8) {
    int d = b * BN + r;
    if (d < N_NODES) {
      float2 s2 = __half22float2(g2[(size_t)d * 32 + sub]);  // self (dinv in g)
      float a0 = acc[r * 64 + sub] + s2.x;
      float a1 = acc[r * 64 + 32 + sub] + s2.y;
      float dv = dinv[d];
      out[(size_t)d * 64 + sub] = fmaf(a0, dv, b0);
      out[(size_t)d * 64 + 32 + sub] = fmaf(a1, dv, b1);
    }
  }
}

// fp32 GEMM for the MLP: C[n,F] = op(A[n,64])@W[64,F] (+bias)(relu).
// Single-phase only (see R6/R8 spill rule).
template <int F>
__global__ __launch_bounds__(256) void gemm_kernel(const float* __restrict__ A, const float* __restrict__ W,
                                                   const float* __restrict__ bias, float* __restrict__ C,
                                                   int n, int reluIn, int reluOut) {
  constexpr int CPT = F / 8;
  __shared__ float Ws[64 * F];
  int t = threadIdx.x;
  for (int i = t; i < 64 * F / 4; i += 256) ((float4*)Ws)[i] = ((const float4*)W)[i];
  __syncthreads();

  int rg = t >> 3, cg = t & 7;
  int r0 = blockIdx.x * 128 + rg * 4;
  int c0 = cg * CPT;

  float acc[4][CPT];
#pragma unroll
  for (int i = 0; i < 4; i++)
#pragma unroll
    for (int j = 0; j < CPT; j++) acc[i][j] = 0.f;

  const float4* A4 = (const float4*)A;
  for (int kk = 0; kk < 16; kk++) {
    float4 a[4];
#pragma unroll
    for (int i = 0; i < 4; i++) {
      int r = r0 + i;
      float4 v = (r < n) ? A4[(size_t)r * 16 + kk] : make_float4(0.f, 0.f, 0.f, 0.f);
      if (reluIn) {
        v.x = fmaxf(v.x, 0.f); v.y = fmaxf(v.y, 0.f);
        v.z = fmaxf(v.z, 0.f); v.w = fmaxf(v.w, 0.f);
      }
      a[i] = v;
    }
#pragma unroll
    for (int q = 0; q < 4; q++) {
      int k = kk * 4 + q;
      float w[CPT];
      if constexpr (CPT % 4 == 0) {
#pragma unroll
        for (int j = 0; j < CPT / 4; j++)
          *(float4*)&w[4 * j] = *(const float4*)&Ws[k * F + c0 + 4 * j];  // ds_read_b128
      } else {
#pragma unroll
        for (int j = 0; j < CPT; j++) w[j] = Ws[k * F + c0 + j];
      }
#pragma unroll
      for (int i = 0; i < 4; i++) {
        float av = q == 0 ? a[i].x : q == 1 ? a[i].y : q == 2 ? a[i].z : a[i].w;
#pragma unroll
        for (int j = 0; j < CPT; j++) acc[i][j] = fmaf(av, w[j], acc[i][j]);
      }
    }
  }

  float bv[CPT];
#pragma unroll
  for (int j = 0; j < CPT; j++) bv[j] = bias ? bias[c0 + j] : 0.f;
#pragma unroll
  for (int i = 0; i < 4; i++) {
    int r = r0 + i;
    if (r < n) {
      float* crow = C + (size_t)r * F + c0;
#pragma unroll
      for (int j = 0; j < CPT; j++) {
        float v = acc[i][j] + bv[j];
        if (reluOut) v = fmaxf(v, 0.f);
        crow[j] = v;
      }
    }
  }
}

}  // namespace

extern "C" void kernel_launch(void* const* d_in, const int* in_sizes, int n_in,
                              void* d_out, int out_size, void* d_ws, size_t ws_size,
                              hipStream_t stream) {
  const float* x   = (const float*)d_in[0];
  const void*  ei  = d_in[1];
  const float* W1  = (const float*)d_in[2];
  const float* b1  = (const float*)d_in[3];
  const float* W2  = (const float*)d_in[4];
  const float* b2  = (const float*)d_in[5];
  const float* Wm1 = (const float*)d_in[6];
  const float* bm1 = (const float*)d_in[7];
  const float* Wm2 = (const float*)d_in[8];
  const float* bm2 = (const float*)d_in[9];
  float* out = (float*)d_out;

  char* ws = (char*)d_ws;
  size_t off = 0;
  auto alloc = [&](size_t bytes) -> void* {
    void* p = ws + off;
    off = (off + bytes + 511) & ~(size_t)511;
    return p;
  };
  int*      bucketCnt = (int*)     alloc((size_t)NBUCK * 4);
  unsigned* tmp       = (unsigned*)alloc((size_t)NBUCK * CAP * 4 + 512);  // +tail slack
  float*    dinv      = (float*)   alloc((size_t)N_NODES * 4);
  __half*   g1        = (__half*)  alloc((size_t)N_NODES * 64 * 2);
  float*    hA        = (float*)   alloc((size_t)N_NODES * 64 * 4);
  float*    hB        = (float*)   alloc((size_t)N_NODES * 64 * 4);
  (void)ws_size; (void)in_sizes; (void)n_in; (void)out_size;

  dim3 b256(256);
  int gGemm = (N_NODES + 127) / 128;
  int gBkt  = (N_EDGES + EPB_A - 1) / EPB_A;

  // preprocessing: bucket-by-dst (unsorted within bucket) + degree histogram
  hipMemsetAsync(bucketCnt, 0, (size_t)NBUCK * 4, stream);
  bucket_kernel<<<gBkt, b256, 0, stream>>>(ei, bucketCnt, tmp);
  deg_kernel<<<NBUCK, b256, 0, stream>>>(tmp, bucketCnt, dinv);

  // conv1: g1 = (x@W1)*dinv (fp16, permuted); hB = dinv*(self+SUM)+b1 (fp32)
  gemm_g_kernel<<<gGemm, b256, 0, stream>>>(x, W1, dinv, g1, 0);
  aggregate_lds<<<NBUCK, b256, 0, stream>>>((const __half2*)g1, tmp, bucketCnt, dinv, b1, hB);

  // conv2: g1 = (relu(hB)@W2)*dinv (fp16, permuted); hB = dinv*(self+SUM)+b2
  gemm_g_kernel<<<gGemm, b256, 0, stream>>>(hB, W2, dinv, g1, 1);
  aggregate_lds<<<NBUCK, b256, 0, stream>>>((const __half2*)g1, tmp, bucketCnt, dinv, b2, hB);

  // MLP: hA = relu(hB@Wm1+bm1); out = hA@Wm2+bm2  (two single-phase GEMMs)
  gemm_kernel<64><<<gGemm, b256, 0, stream>>>(hB, Wm1, bm1, hA, N_NODES, 0, 1);
  gemm_kernel<40><<<gGemm, b256, 0, stream>>>(hA, Wm2, bm2, out, N_NODES, 0, 0);
}

// Round 2
// 268.518 us; speedup vs baseline: 3.9883x; 3.9883x over previous
//
#include <hip/hip_runtime.h>
#include <hip/hip_bf16.h>
#include <hip/hip_fp16.h>

// GCN: h1 = relu(GCNConv(x,W1,b1)); h2 = GCNConv(h1,W2,b2);
//      h3 = relu(h2@Wm1+bm1); out = h3@Wm2+bm2
// R2: CSR-by-dst gather-reduce replaced scatter atomics (10x write amp).
// R4: 2-pass XCD-local bucket sort. R5: dinv folded into GEMM epilogue.
// R6/R8 FAILED: multi-phase LDS GEMM fusion -> spills. R7: fp16 g-tables.
// R9: 2-node/wave gather aggregate (255.8us). R13 FAILED: pad-4/4-wide
//      (latency-bound; needs 8-deep pipeline). R14: cleanup (253.7us).
// R15 FAILED (1071us): scatter-side LDS aggregation. 782 blocks (vs 12500)
//      + ~20 serial vmcnt-drain rounds/wave -> pure latency serialization
//      (HBM 2.3%, VALU 2%, occ 22%). Binding resource is latency-hiding
//      slack, NOT instruction count/traffic. Reverted.
// R16: R14 gather aggregate restored verbatim, plus:
//      (a) 128-node buckets (NBUCK=782, CAP=2560): csr_kernel was 196
//          blocks x 36.5KB LDS = 0.77 blocks/CU (half machine idle);
//          now 782 blocks x ~11KB.
//      (b) degree-class sort -> perm[]: aggregate wave pairs nodes with
//          equal trip counts, killing the E[max(t0,t1)]-E[t] ~12% of
//          padded gather slots lost to exec-mask divergence.

namespace {

constexpr int N_NODES = 100000;
constexpr int N_EDGES = 1000000;
constexpr int BN = 128;                         // dst nodes per bucket
constexpr int NBUCK = (N_NODES + BN - 1) / BN;  // 782 buckets
constexpr int CAP = 2560;    // padded edges/bucket: mean ~1728, sd ~45 -> +18 sd
constexpr int EPB_A = 2048;  // edges per passA block

// passA: partition edges into NBUCK buckets by dst>>7. word=(src<<7)|(dst&127)
// (17+7=24 bits). Per-block int32/int64 detection: sample 512 odd words of own
// range (int64 high halves are all 0; int32 node ids ~surely not).
__global__ __launch_bounds__(256) void bucket_kernel(const void* __restrict__ ei,
                                                     int* __restrict__ bucketCnt,
                                                     unsigned* __restrict__ tmp) {
  __shared__ int hist[NBUCK];
  __shared__ int basePB[NBUCK];
  __shared__ int cur[NBUCK];
  __shared__ int sflag;
  int t = threadIdx.x;
  for (int i = t; i < NBUCK; i += 256) { hist[i] = 0; cur[i] = 0; }
  if (t == 0) sflag = 0;
  __syncthreads();

  int e0 = blockIdx.x * EPB_A;
  const unsigned* w = (const unsigned*)ei;
  unsigned any = 0;
#pragma unroll
  for (int s = 0; s < 2; s++) {
    int e = e0 + s * 256 + t;
    if (e < N_EDGES) any |= w[2 * e + 1];
  }
  if (any) sflag = 1;  // benign race, all writers store 1
  __syncthreads();
  int is32 = sflag;

  unsigned wreg[8];
  int breg[8];
#pragma unroll
  for (int k = 0; k < 8; k++) {
    int e = e0 + k * 256 + t;
    breg[k] = -1;
    if (e < N_EDGES) {
      int s, d;
      if (is32) {
        const int* p = (const int*)ei;
        s = p[e]; d = p[N_EDGES + e];
      } else {
        const long long* p = (const long long*)ei;
        s = (int)p[e]; d = (int)p[N_EDGES + e];
      }
      wreg[k] = ((unsigned)s << 7) | (unsigned)(d & 127);
      breg[k] = d >> 7;
      atomicAdd(&hist[breg[k]], 1);
    }
  }
  __syncthreads();
  for (int i = t; i < NBUCK; i += 256)
    basePB[i] = hist[i] ? atomicAdd(&bucketCnt[i], hist[i]) : 0;
  __syncthreads();
#pragma unroll
  for (int k = 0; k < 8; k++) {
    if (breg[k] >= 0) {
      int r = atomicAdd(&cur[breg[k]], 1);
      tmp[(size_t)breg[k] * CAP + basePB[breg[k]] + r] = wreg[k];
    }
  }
}

// passB: one block per 128-node bucket, 256 thr. LDS counting sort; rows
// padded to mult 8 with sentinel N_NODES (zero row); emits row_start/row_end,
// dinv, and perm[] (nodes degree-class-sorted within bucket so the aggregate
// pairs equal-trip-count nodes in a wave).
__global__ __launch_bounds__(256) void csr_kernel(const unsigned* __restrict__ tmp,
                                                  const int* __restrict__ bucketCnt,
                                                  int* __restrict__ col,
                                                  int* __restrict__ row_start,
                                                  int* __restrict__ row_end,
                                                  int* __restrict__ perm,
                                                  float* __restrict__ dinv) {
  __shared__ int sc[BN];
  __shared__ int hist[BN];
  __shared__ int chist[33];
  __shared__ int cbase[33];
  __shared__ unsigned stage[CAP];
  int b = blockIdx.x, t = threadIdx.x;
  int myCnt = bucketCnt[b];
  int base = b * CAP;
  int nb = min(BN, N_NODES - b * BN);

  if (t < BN) hist[t] = 0;
  if (t < 33) chist[t] = 0;
  __syncthreads();
  for (int i = t; i < myCnt; i += 256) {
    unsigned w = tmp[base + i];
    stage[i] = w;
    atomicAdd(&hist[w & 127u], 1);
  }
  __syncthreads();

  int deg = (t < BN) ? hist[t] : 0;
  int pdeg = (deg + 7) & ~7;  // pad rows to mult 8 (R9-proven 8-deep pipeline)
  if (t < BN) sc[t] = pdeg;
  __syncthreads();
  for (int off = 1; off < BN; off <<= 1) {
    int u = (t >= off && t < BN) ? sc[t - off] : 0;
    __syncthreads();
    if (t < BN) sc[t] += u;
    __syncthreads();
  }
  int pexcl = (t < BN) ? sc[t] - pdeg : 0;
  int d = b * BN + t;
  if (t < nb) {
    row_start[d] = base + pexcl;
    row_end[d] = base + pexcl + pdeg;
    dinv[d] = rsqrtf((float)deg + 1.0f);
  }
  __syncthreads();
  if (t < BN) hist[t] = pexcl;  // reuse as scatter cursor
  __syncthreads();
  for (int i = t; i < myCnt; i += 256) {
    unsigned w = stage[i];
    int pos = atomicAdd(&hist[w & 127u], 1);
    col[base + pos] = (int)(w >> 7);
  }
  if (t < nb)
    for (int j = deg; j < pdeg; j++) col[base + pexcl + j] = N_NODES;

  // degree-class counting sort -> perm (class = trip count = pdeg/8)
  int cls = min(pdeg >> 3, 32);
  int idx = 0;
  if (t < nb) idx = atomicAdd(&chist[cls], 1);
  __syncthreads();
  if (t == 0) {
    int run = 0;
    for (int c = 0; c <= 32; c++) { cbase[c] = run; run += chist[c]; }
  }
  __syncthreads();
  if (t < nb) perm[b * BN + cbase[cls] + idx] = d;
}

__device__ inline uint4 pack_half8(const float* v) {
  __half2 h0 = __floats2half2_rn(v[0], v[1]);
  __half2 h1 = __floats2half2_rn(v[2], v[3]);
  __half2 h2 = __floats2half2_rn(v[4], v[5]);
  __half2 h3 = __floats2half2_rn(v[6], v[7]);
  uint4 u;
  u.x = *(unsigned*)&h0; u.y = *(unsigned*)&h1;
  u.z = *(unsigned*)&h2; u.w = *(unsigned*)&h3;
  return u;
}

// g[r] = (op(A[r])@W) * dinv[r], fp16 out, zero pad row N_NODES.
// 128 rows/block, 256 thr, thread = 4 rows x 8 cols. W staged in LDS.
__global__ __launch_bounds__(256) void gemm_g_kernel(const float* __restrict__ A,
                                                     const float* __restrict__ W,
                                                     const float* __restrict__ dinv,
                                                     __half* __restrict__ g,
                                                     int reluIn) {
  __shared__ float Ws[64 * 64];
  int t = threadIdx.x;
  if (blockIdx.x == 0 && t < 32) ((float*)(g + (size_t)N_NODES * 64))[t] = 0.f;  // pad row
  for (int i = t; i < 64 * 64 / 4; i += 256) ((float4*)Ws)[i] = ((const float4*)W)[i];
  __syncthreads();

  int rg = t >> 3, cg = t & 7;
  int r0 = blockIdx.x * 128 + rg * 4;
  int c0 = cg * 8;

  float acc[4][8];
#pragma unroll
  for (int i = 0; i < 4; i++)
#pragma unroll
    for (int j = 0; j < 8; j++) acc[i][j] = 0.f;

  const float4* A4 = (const float4*)A;
  for (int kk = 0; kk < 16; kk++) {
    float4 a[4];
#pragma unroll
    for (int i = 0; i < 4; i++) {
      int r = r0 + i;
      float4 v = (r < N_NODES) ? A4[(size_t)r * 16 + kk] : make_float4(0.f, 0.f, 0.f, 0.f);
      if (reluIn) {
        v.x = fmaxf(v.x, 0.f); v.y = fmaxf(v.y, 0.f);
        v.z = fmaxf(v.z, 0.f); v.w = fmaxf(v.w, 0.f);
      }
      a[i] = v;
    }
#pragma unroll
    for (int q = 0; q < 4; q++) {
      int k = kk * 4 + q;
      float w[8];
#pragma unroll
      for (int j = 0; j < 2; j++) *(float4*)&w[4 * j] = *(const float4*)&Ws[k * 64 + c0 + 4 * j];
#pragma unroll
      for (int i = 0; i < 4; i++) {
        float av = q == 0 ? a[i].x : q == 1 ? a[i].y : q == 2 ? a[i].z : a[i].w;
#pragma unroll
        for (int j = 0; j < 8; j++) acc[i][j] = fmaf(av, w[j], acc[i][j]);
      }
    }
  }
#pragma unroll
  for (int i = 0; i < 4; i++) {
    int r = r0 + i;
    if (r < N_NODES) {
      float s = dinv[r];
#pragma unroll
      for (int j = 0; j < 8; j++) acc[i][j] *= s;
      *(uint4*)(g + (size_t)r * 64 + c0) = pack_half8(acc[i]);
    }
  }
}

// Per-node gather-reduce, 2 nodes per wave (R9-proven): lanes 0-31 node d0,
// lanes 32-63 node d1; each lane covers 2 features as one half2 -> one
// gather instr fetches TWO 128B rows; 8-deep gather pipeline. Half-wave
// edge loops diverge on exec mask. Node slots indirected through perm[] so
// paired nodes have equal trip counts (R16). fp32 accum/out. grid*8 == N.
__global__ __launch_bounds__(256) void aggregate_kernel(const __half* __restrict__ g,
                                                        const int* __restrict__ col,
                                                        const int* __restrict__ row_start,
                                                        const int* __restrict__ row_end,
                                                        const int* __restrict__ perm,
                                                        const float* __restrict__ dinv,
                                                        const float* __restrict__ bias,
                                                        float* __restrict__ out) {
  int wave = threadIdx.x >> 6;
  int lane = threadIdx.x & 63;
  int half = lane >> 5;
  int sub = lane & 31;
  int d = perm[blockIdx.x * 8 + wave * 2 + half];

  const __half2* g2 = (const __half2*)g;
  int e0 = row_start[d];
  int len = row_end[d] - e0;

  float2 a0 = __half22float2(g2[(size_t)d * 32 + sub]);  // self (dinv in g)
  float2 a1 = {0.f, 0.f}, a2 = {0.f, 0.f}, a3 = {0.f, 0.f};
  float2 a4 = {0.f, 0.f}, a5 = {0.f, 0.f}, a6 = {0.f, 0.f}, a7 = {0.f, 0.f};

  for (int i = 0; i < len; i += 8) {  // per-half-wave trip count (exec-mask divergence)
    int4 ca = *(const int4*)(col + e0 + i);
    int4 cb = *(const int4*)(col + e0 + i + 4);
    float2 h0 = __half22float2(g2[(size_t)ca.x * 32 + sub]);
    float2 h1 = __half22float2(g2[(size_t)ca.y * 32 + sub]);
    float2 h2 = __half22float2(g2[(size_t)ca.z * 32 + sub]);
    float2 h3 = __half22float2(g2[(size_t)ca.w * 32 + sub]);
    float2 h4 = __half22float2(g2[(size_t)cb.x * 32 + sub]);
    float2 h5 = __half22float2(g2[(size_t)cb.y * 32 + sub]);
    float2 h6 = __half22float2(g2[(size_t)cb.z * 32 + sub]);
    float2 h7 = __half22float2(g2[(size_t)cb.w * 32 + sub]);
    a0.x += h0.x; a0.y += h0.y; a1.x += h1.x; a1.y += h1.y;
    a2.x += h2.x; a2.y += h2.y; a3.x += h3.x; a3.y += h3.y;
    a4.x += h4.x; a4.y += h4.y; a5.x += h5.x; a5.y += h5.y;
    a6.x += h6.x; a6.y += h6.y; a7.x += h7.x; a7.y += h7.y;
  }
  float rx = ((a0.x + a1.x) + (a2.x + a3.x)) + ((a4.x + a5.x) + (a6.x + a7.x));
  float ry = ((a0.y + a1.y) + (a2.y + a3.y)) + ((a4.y + a5.y) + (a6.y + a7.y));
  float dv = dinv[d];
  float2 bv = ((const float2*)bias)[sub];
  float2 o;
  o.x = fmaf(rx, dv, bv.x);
  o.y = fmaf(ry, dv, bv.y);
  ((float2*)out)[(size_t)d * 32 + sub] = o;
}

// fp32 GEMM for the MLP: C[n,F] = op(A[n,64])@W[64,F] (+bias)(relu).
// Single-phase only (see R6/R8 spill rule).
template <int F>
__global__ __launch_bounds__(256) void gemm_kernel(const float* __restrict__ A, const float* __restrict__ W,
                                                   const float* __restrict__ bias, float* __restrict__ C,
                                                   int n, int reluIn, int reluOut) {
  constexpr int CPT = F / 8;
  __shared__ float Ws[64 * F];
  int t = threadIdx.x;
  for (int i = t; i < 64 * F / 4; i += 256) ((float4*)Ws)[i] = ((const float4*)W)[i];
  __syncthreads();

  int rg = t >> 3, cg = t & 7;
  int r0 = blockIdx.x * 128 + rg * 4;
  int c0 = cg * CPT;

  float acc[4][CPT];
#pragma unroll
  for (int i = 0; i < 4; i++)
#pragma unroll
    for (int j = 0; j < CPT; j++) acc[i][j] = 0.f;

  const float4* A4 = (const float4*)A;
  for (int kk = 0; kk < 16; kk++) {
    float4 a[4];
#pragma unroll
    for (int i = 0; i < 4; i++) {
      int r = r0 + i;
      float4 v = (r < n) ? A4[(size_t)r * 16 + kk] : make_float4(0.f, 0.f, 0.f, 0.f);
      if (reluIn) {
        v.x = fmaxf(v.x, 0.f); v.y = fmaxf(v.y, 0.f);
        v.z = fmaxf(v.z, 0.f); v.w = fmaxf(v.w, 0.f);
      }
      a[i] = v;
    }
#pragma unroll
    for (int q = 0; q < 4; q++) {
      int k = kk * 4 + q;
      float w[CPT];
      if constexpr (CPT % 4 == 0) {
#pragma unroll
        for (int j = 0; j < CPT / 4; j++)
          *(float4*)&w[4 * j] = *(const float4*)&Ws[k * F + c0 + 4 * j];  // ds_read_b128
      } else {
#pragma unroll
        for (int j = 0; j < CPT; j++) w[j] = Ws[k * F + c0 + j];
      }
#pragma unroll
      for (int i = 0; i < 4; i++) {
        float av = q == 0 ? a[i].x : q == 1 ? a[i].y : q == 2 ? a[i].z : a[i].w;
#pragma unroll
        for (int j = 0; j < CPT; j++) acc[i][j] = fmaf(av, w[j], acc[i][j]);
      }
    }
  }

  float bv[CPT];
#pragma unroll
  for (int j = 0; j < CPT; j++) bv[j] = bias ? bias[c0 + j] : 0.f;
#pragma unroll
  for (int i = 0; i < 4; i++) {
    int r = r0 + i;
    if (r < n) {
      float* crow = C + (size_t)r * F + c0;
#pragma unroll
      for (int j = 0; j < CPT; j++) {
        float v = acc[i][j] + bv[j];
        if (reluOut) v = fmaxf(v, 0.f);
        crow[j] = v;
      }
    }
  }
}

}  // namespace

extern "C" void kernel_launch(void* const* d_in, const int* in_sizes, int n_in,
                              void* d_out, int out_size, void* d_ws, size_t ws_size,
                              hipStream_t stream) {
  const float* x   = (const float*)d_in[0];
  const void*  ei  = d_in[1];
  const float* W1  = (const float*)d_in[2];
  const float* b1  = (const float*)d_in[3];
  const float* W2  = (const float*)d_in[4];
  const float* b2  = (const float*)d_in[5];
  const float* Wm1 = (const float*)d_in[6];
  const float* bm1 = (const float*)d_in[7];
  const float* Wm2 = (const float*)d_in[8];
  const float* bm2 = (const float*)d_in[9];
  float* out = (float*)d_out;

  char* ws = (char*)d_ws;
  size_t off = 0;
  auto alloc = [&](size_t bytes) -> void* {
    void* p = ws + off;
    off = (off + bytes + 511) & ~(size_t)511;
    return p;
  };
  int*      bucketCnt = (int*)     alloc((size_t)NBUCK * 4);
  unsigned* tmp       = (unsigned*)alloc((size_t)NBUCK * CAP * 4);  // 8.0 MB
  int*      colA      = (int*)     alloc((size_t)NBUCK * CAP * 4);  // 8.0 MB
  int*      rowS      = (int*)     alloc((size_t)N_NODES * 4);
  int*      rowE      = (int*)     alloc((size_t)N_NODES * 4);
  int*      perm      = (int*)     alloc((size_t)N_NODES * 4);
  float*    dinv      = (float*)   alloc((size_t)N_NODES * 4);
  __half*   g1        = (__half*)  alloc((size_t)(N_NODES + 1) * 64 * 2);  // +1 zero row
  float*    hA        = (float*)   alloc((size_t)N_NODES * 64 * 4);
  float*    hB        = (float*)   alloc((size_t)N_NODES * 64 * 4);
  (void)ws_size; (void)in_sizes; (void)n_in; (void)out_size;

  dim3 b256(256);
  int gGemm = (N_NODES + 127) / 128;
  int gAgg  = N_NODES / 8;  // 12500, exact
  int gBkt  = (N_EDGES + EPB_A - 1) / EPB_A;

  // preprocessing: 2-pass bucket sort -> padded CSR + pairing perm
  hipMemsetAsync(bucketCnt, 0, (size_t)NBUCK * 4, stream);
  bucket_kernel<<<gBkt, b256, 0, stream>>>(ei, bucketCnt, tmp);
  csr_kernel<<<NBUCK, dim3(256), 0, stream>>>(tmp, bucketCnt, colA, rowS, rowE, perm, dinv);

  // conv1: g1 = (x@W1)*dinv (fp16); hB = dinv*(self+SUM)+b1 (fp32)
  gemm_g_kernel<<<gGemm, b256, 0, stream>>>(x, W1, dinv, g1, 0);
  aggregate_kernel<<<gAgg, b256, 0, stream>>>(g1, colA, rowS, rowE, perm, dinv, b1, hB);

  // conv2: g1 = (relu(hB)@W2)*dinv (fp16); hB = dinv*(self+SUM)+b2 (fp32)
  gemm_g_kernel<<<gGemm, b256, 0, stream>>>(hB, W2, dinv, g1, 1);
  aggregate_kernel<<<gAgg, b256, 0, stream>>>(g1, colA, rowS, rowE, perm, dinv, b2, hB);

  // MLP: hA = relu(hB@Wm1+bm1); out = hA@Wm2+bm2  (two single-phase GEMMs)
  gemm_kernel<64><<<gGemm, b256, 0, stream>>>(hB, Wm1, bm1, hA, N_NODES, 0, 1);
  gemm_kernel<40><<<gGemm, b256, 0, stream>>>(hA, Wm2, bm2, out, N_NODES, 0, 0);
}

// Round 3
// 252.229 us; speedup vs baseline: 4.2459x; 1.0646x over previous
//
#include <hip/hip_runtime.h>
#include <hip/hip_bf16.h>
#include <hip/hip_fp16.h>

// GCN: h1 = relu(GCNConv(x,W1,b1)); h2 = GCNConv(h1,W2,b2);
//      h3 = relu(h2@Wm1+bm1); out = h3@Wm2+bm2
// R2: CSR-by-dst gather-reduce replaced scatter atomics (10x write amp).
// R4: 2-pass XCD-local bucket sort. R5: dinv folded into GEMM epilogue.
// R6/R8 FAILED: multi-phase LDS GEMM fusion -> spills. R7: fp16 g-tables.
// R9: 2-node/wave aggregate, 8-deep (255.8us). R13 FAILED: 4-deep (263us).
// R14: cleanup (253.7us). R15 FAILED (1071us): scatter-side LDS agg -- 16x
//      fewer waves + serial vmcnt rounds; binding resource is latency-hiding
//      slack (outstanding gathers), not instruction count or traffic.
// R16 FAILED (268.5us): perm pairing + 128-node csr buckets. Padding/
//      divergence waste is sentinel gathers on an L1-hot zero row == cheap
//      slots, so perm saved nothing and cost indirection. Reverted.
// R17: R14 structure verbatim, ONE change: gather pipeline depth 8 -> 16
//      (pad-16 rows). 16 outstanding gathers/half-wave vs 600cyc L3-ish
//      latency; single trip for 97% of nodes (divergence gone for free);
//      grid unchanged at 12500 blocks. Aggregate FETCH/dispatch ~63MB
//      (unchanged); predicted agg ~90 -> ~65-70us each.

namespace {

constexpr int N_NODES = 100000;
constexpr int N_EDGES = 1000000;
constexpr int NBUCK = (N_NODES + 511) / 512;  // 196 buckets of 512 nodes
constexpr int CAP_RAW = 8192;   // raw edges/bucket (mean 5120, sd ~71)
constexpr int CAP_COL = 12288;  // pad-16 edges/bucket (mean ~8400, sd ~80)
constexpr int EPB_A = 2048;     // edges per passA block

// passA: partition edges into NBUCK buckets by dst>>9. word=(src<<9)|(dst&511).
// Per-block int32/int64 detection: sample 512 odd words of own range (int64
// high halves are all 0; int32 node ids ~surely not).
__global__ __launch_bounds__(256) void bucket_kernel(const void* __restrict__ ei,
                                                     int* __restrict__ bucketCnt,
                                                     unsigned* __restrict__ tmp) {
  __shared__ int hist[NBUCK];
  __shared__ int basePB[NBUCK];
  __shared__ int cur[NBUCK];
  __shared__ int sflag;
  int t = threadIdx.x;
  if (t < NBUCK) { hist[t] = 0; cur[t] = 0; }
  if (t == 0) sflag = 0;
  __syncthreads();

  int e0 = blockIdx.x * EPB_A;
  const unsigned* w = (const unsigned*)ei;
  unsigned any = 0;
#pragma unroll
  for (int s = 0; s < 2; s++) {
    int e = e0 + s * 256 + t;
    if (e < N_EDGES) any |= w[2 * e + 1];
  }
  if (any) sflag = 1;  // benign race, all writers store 1
  __syncthreads();
  int is32 = sflag;

  unsigned wreg[8];
  int breg[8];
#pragma unroll
  for (int k = 0; k < 8; k++) {
    int e = e0 + k * 256 + t;
    breg[k] = -1;
    if (e < N_EDGES) {
      int s, d;
      if (is32) {
        const int* p = (const int*)ei;
        s = p[e]; d = p[N_EDGES + e];
      } else {
        const long long* p = (const long long*)ei;
        s = (int)p[e]; d = (int)p[N_EDGES + e];
      }
      wreg[k] = ((unsigned)s << 9) | (unsigned)(d & 511);
      breg[k] = d >> 9;
      atomicAdd(&hist[breg[k]], 1);
    }
  }
  __syncthreads();
  if (t < NBUCK) basePB[t] = hist[t] ? atomicAdd(&bucketCnt[t], hist[t]) : 0;
  __syncthreads();
#pragma unroll
  for (int k = 0; k < 8; k++) {
    if (breg[k] >= 0) {
      int r = atomicAdd(&cur[breg[k]], 1);
      tmp[(size_t)breg[k] * CAP_RAW + basePB[breg[k]] + r] = wreg[k];
    }
  }
}

// passB: one block per bucket. LDS counting sort; rows padded to mult 16 with
// sentinel N_NODES (zero row); emit row_start/row_end + dinv.
__global__ __launch_bounds__(512) void csr_kernel(const unsigned* __restrict__ tmp,
                                                  const int* __restrict__ bucketCnt,
                                                  int* __restrict__ col,
                                                  int* __restrict__ row_start,
                                                  int* __restrict__ row_end,
                                                  float* __restrict__ dinv) {
  __shared__ int sc[512];
  __shared__ int hist[512];
  __shared__ unsigned stage[CAP_RAW];
  int b = blockIdx.x, t = threadIdx.x;
  int myCnt = bucketCnt[b];
  int baseT = b * CAP_RAW;
  int baseC = b * CAP_COL;

  hist[t] = 0;
  __syncthreads();
  for (int i = t; i < myCnt; i += 512) {
    unsigned w = tmp[(size_t)baseT + i];
    stage[i] = w;
    atomicAdd(&hist[w & 511u], 1);
  }
  __syncthreads();

  int deg = hist[t];
  int pdeg = (deg + 15) & ~15;  // pad rows to mult 16 (R17: 16-deep pipeline)
  sc[t] = pdeg;
  __syncthreads();
#pragma unroll
  for (int off = 1; off < 512; off <<= 1) {
    int u = (t >= off) ? sc[t - off] : 0;
    __syncthreads();
    sc[t] += u;
    __syncthreads();
  }
  int pexcl = sc[t] - pdeg;
  int d = b * 512 + t;
  if (d < N_NODES) {
    row_start[d] = baseC + pexcl;
    row_end[d] = baseC + pexcl + pdeg;
    dinv[d] = rsqrtf((float)deg + 1.0f);
  }
  __syncthreads();
  hist[t] = pexcl;
  __syncthreads();
  for (int i = t; i < myCnt; i += 512) {
    unsigned w = stage[i];
    int pos = atomicAdd(&hist[w & 511u], 1);
    col[baseC + pos] = (int)(w >> 9);
  }
  for (int j = deg; j < pdeg; j++) col[baseC + pexcl + j] = N_NODES;
}

__device__ inline uint4 pack_half8(const float* v) {
  __half2 h0 = __floats2half2_rn(v[0], v[1]);
  __half2 h1 = __floats2half2_rn(v[2], v[3]);
  __half2 h2 = __floats2half2_rn(v[4], v[5]);
  __half2 h3 = __floats2half2_rn(v[6], v[7]);
  uint4 u;
  u.x = *(unsigned*)&h0; u.y = *(unsigned*)&h1;
  u.z = *(unsigned*)&h2; u.w = *(unsigned*)&h3;
  return u;
}

// g[r] = (op(A[r])@W) * dinv[r], fp16 out, zero pad row N_NODES.
// 128 rows/block, 256 thr, thread = 4 rows x 8 cols. W staged in LDS.
__global__ __launch_bounds__(256) void gemm_g_kernel(const float* __restrict__ A,
                                                     const float* __restrict__ W,
                                                     const float* __restrict__ dinv,
                                                     __half* __restrict__ g,
                                                     int reluIn) {
  __shared__ float Ws[64 * 64];
  int t = threadIdx.x;
  if (blockIdx.x == 0 && t < 32) ((float*)(g + (size_t)N_NODES * 64))[t] = 0.f;  // pad row
  for (int i = t; i < 64 * 64 / 4; i += 256) ((float4*)Ws)[i] = ((const float4*)W)[i];
  __syncthreads();

  int rg = t >> 3, cg = t & 7;
  int r0 = blockIdx.x * 128 + rg * 4;
  int c0 = cg * 8;

  float acc[4][8];
#pragma unroll
  for (int i = 0; i < 4; i++)
#pragma unroll
    for (int j = 0; j < 8; j++) acc[i][j] = 0.f;

  const float4* A4 = (const float4*)A;
  for (int kk = 0; kk < 16; kk++) {
    float4 a[4];
#pragma unroll
    for (int i = 0; i < 4; i++) {
      int r = r0 + i;
      float4 v = (r < N_NODES) ? A4[(size_t)r * 16 + kk] : make_float4(0.f, 0.f, 0.f, 0.f);
      if (reluIn) {
        v.x = fmaxf(v.x, 0.f); v.y = fmaxf(v.y, 0.f);
        v.z = fmaxf(v.z, 0.f); v.w = fmaxf(v.w, 0.f);
      }
      a[i] = v;
    }
#pragma unroll
    for (int q = 0; q < 4; q++) {
      int k = kk * 4 + q;
      float w[8];
#pragma unroll
      for (int j = 0; j < 2; j++) *(float4*)&w[4 * j] = *(const float4*)&Ws[k * 64 + c0 + 4 * j];
#pragma unroll
      for (int i = 0; i < 4; i++) {
        float av = q == 0 ? a[i].x : q == 1 ? a[i].y : q == 2 ? a[i].z : a[i].w;
#pragma unroll
        for (int j = 0; j < 8; j++) acc[i][j] = fmaf(av, w[j], acc[i][j]);
      }
    }
  }
#pragma unroll
  for (int i = 0; i < 4; i++) {
    int r = r0 + i;
    if (r < N_NODES) {
      float s = dinv[r];
#pragma unroll
      for (int j = 0; j < 8; j++) acc[i][j] *= s;
      *(uint4*)(g + (size_t)r * 64 + c0) = pack_half8(acc[i]);
    }
  }
}

// Per-node gather-reduce, 2 nodes per wave (R9-proven): lanes 0-31 node d0,
// lanes 32-63 node d1; each lane covers 2 features as one half2 -> one
// gather instr fetches TWO 128B rows; 16-deep gather pipeline (R17).
// Half-wave edge loops diverge on exec mask (rare at pad-16: P(2 trips)~3%).
// fp32 accum/out. grid*8 == N_NODES.
__global__ __launch_bounds__(256) void aggregate_kernel(const __half* __restrict__ g,
                                                        const int* __restrict__ col,
                                                        const int* __restrict__ row_start,
                                                        const int* __restrict__ row_end,
                                                        const float* __restrict__ dinv,
                                                        const float* __restrict__ bias,
                                                        float* __restrict__ out) {
  int wave = threadIdx.x >> 6;
  int lane = threadIdx.x & 63;
  int half = lane >> 5;
  int sub = lane & 31;
  int d = blockIdx.x * 8 + wave * 2 + half;

  const __half2* g2 = (const __half2*)g;
  int e0 = row_start[d];
  int len = row_end[d] - e0;

  float2 a0 = __half22float2(g2[(size_t)d * 32 + sub]);  // self (dinv in g)
  float2 a1 = {0.f, 0.f}, a2 = {0.f, 0.f}, a3 = {0.f, 0.f};
  float2 a4 = {0.f, 0.f}, a5 = {0.f, 0.f}, a6 = {0.f, 0.f}, a7 = {0.f, 0.f};

  for (int i = 0; i < len; i += 16) {  // per-half-wave trip count (exec-mask divergence)
    int4 ca = *(const int4*)(col + e0 + i);
    int4 cb = *(const int4*)(col + e0 + i + 4);
    int4 cc = *(const int4*)(col + e0 + i + 8);
    int4 cd = *(const int4*)(col + e0 + i + 12);
    float2 h0 = __half22float2(g2[(size_t)ca.x * 32 + sub]);
    float2 h1 = __half22float2(g2[(size_t)ca.y * 32 + sub]);
    float2 h2 = __half22float2(g2[(size_t)ca.z * 32 + sub]);
    float2 h3 = __half22float2(g2[(size_t)ca.w * 32 + sub]);
    float2 h4 = __half22float2(g2[(size_t)cb.x * 32 + sub]);
    float2 h5 = __half22float2(g2[(size_t)cb.y * 32 + sub]);
    float2 h6 = __half22float2(g2[(size_t)cb.z * 32 + sub]);
    float2 h7 = __half22float2(g2[(size_t)cb.w * 32 + sub]);
    float2 h8 = __half22float2(g2[(size_t)cc.x * 32 + sub]);
    float2 h9 = __half22float2(g2[(size_t)cc.y * 32 + sub]);
    float2 hA = __half22float2(g2[(size_t)cc.z * 32 + sub]);
    float2 hB = __half22float2(g2[(size_t)cc.w * 32 + sub]);
    float2 hC = __half22float2(g2[(size_t)cd.x * 32 + sub]);
    float2 hD = __half22float2(g2[(size_t)cd.y * 32 + sub]);
    float2 hE = __half22float2(g2[(size_t)cd.z * 32 + sub]);
    float2 hF = __half22float2(g2[(size_t)cd.w * 32 + sub]);
    a0.x += h0.x; a0.y += h0.y; a1.x += h1.x; a1.y += h1.y;
    a2.x += h2.x; a2.y += h2.y; a3.x += h3.x; a3.y += h3.y;
    a4.x += h4.x; a4.y += h4.y; a5.x += h5.x; a5.y += h5.y;
    a6.x += h6.x; a6.y += h6.y; a7.x += h7.x; a7.y += h7.y;
    a0.x += h8.x; a0.y += h8.y; a1.x += h9.x; a1.y += h9.y;
    a2.x += hA.x; a2.y += hA.y; a3.x += hB.x; a3.y += hB.y;
    a4.x += hC.x; a4.y += hC.y; a5.x += hD.x; a5.y += hD.y;
    a6.x += hE.x; a6.y += hE.y; a7.x += hF.x; a7.y += hF.y;
  }
  float rx = ((a0.x + a1.x) + (a2.x + a3.x)) + ((a4.x + a5.x) + (a6.x + a7.x));
  float ry = ((a0.y + a1.y) + (a2.y + a3.y)) + ((a4.y + a5.y) + (a6.y + a7.y));
  float dv = dinv[d];
  float2 bv = ((const float2*)bias)[sub];
  float2 o;
  o.x = fmaf(rx, dv, bv.x);
  o.y = fmaf(ry, dv, bv.y);
  ((float2*)out)[(size_t)d * 32 + sub] = o;
}

// fp32 GEMM for the MLP: C[n,F] = op(A[n,64])@W[64,F] (+bias)(relu).
// Single-phase only (see R6/R8 spill rule).
template <int F>
__global__ __launch_bounds__(256) void gemm_kernel(const float* __restrict__ A, const float* __restrict__ W,
                                                   const float* __restrict__ bias, float* __restrict__ C,
                                                   int n, int reluIn, int reluOut) {
  constexpr int CPT = F / 8;
  __shared__ float Ws[64 * F];
  int t = threadIdx.x;
  for (int i = t; i < 64 * F / 4; i += 256) ((float4*)Ws)[i] = ((const float4*)W)[i];
  __syncthreads();

  int rg = t >> 3, cg = t & 7;
  int r0 = blockIdx.x * 128 + rg * 4;
  int c0 = cg * CPT;

  float acc[4][CPT];
#pragma unroll
  for (int i = 0; i < 4; i++)
#pragma unroll
    for (int j = 0; j < CPT; j++) acc[i][j] = 0.f;

  const float4* A4 = (const float4*)A;
  for (int kk = 0; kk < 16; kk++) {
    float4 a[4];
#pragma unroll
    for (int i = 0; i < 4; i++) {
      int r = r0 + i;
      float4 v = (r < n) ? A4[(size_t)r * 16 + kk] : make_float4(0.f, 0.f, 0.f, 0.f);
      if (reluIn) {
        v.x = fmaxf(v.x, 0.f); v.y = fmaxf(v.y, 0.f);
        v.z = fmaxf(v.z, 0.f); v.w = fmaxf(v.w, 0.f);
      }
      a[i] = v;
    }
#pragma unroll
    for (int q = 0; q < 4; q++) {
      int k = kk * 4 + q;
      float w[CPT];
      if constexpr (CPT % 4 == 0) {
#pragma unroll
        for (int j = 0; j < CPT / 4; j++)
          *(float4*)&w[4 * j] = *(const float4*)&Ws[k * F + c0 + 4 * j];  // ds_read_b128
      } else {
#pragma unroll
        for (int j = 0; j < CPT; j++) w[j] = Ws[k * F + c0 + j];
      }
#pragma unroll
      for (int i = 0; i < 4; i++) {
        float av = q == 0 ? a[i].x : q == 1 ? a[i].y : q == 2 ? a[i].z : a[i].w;
#pragma unroll
        for (int j = 0; j < CPT; j++) acc[i][j] = fmaf(av, w[j], acc[i][j]);
      }
    }
  }

  float bv[CPT];
#pragma unroll
  for (int j = 0; j < CPT; j++) bv[j] = bias ? bias[c0 + j] : 0.f;
#pragma unroll
  for (int i = 0; i < 4; i++) {
    int r = r0 + i;
    if (r < n) {
      float* crow = C + (size_t)r * F + c0;
#pragma unroll
      for (int j = 0; j < CPT; j++) {
        float v = acc[i][j] + bv[j];
        if (reluOut) v = fmaxf(v, 0.f);
        crow[j] = v;
      }
    }
  }
}

}  // namespace

extern "C" void kernel_launch(void* const* d_in, const int* in_sizes, int n_in,
                              void* d_out, int out_size, void* d_ws, size_t ws_size,
                              hipStream_t stream) {
  const float* x   = (const float*)d_in[0];
  const void*  ei  = d_in[1];
  const float* W1  = (const float*)d_in[2];
  const float* b1  = (const float*)d_in[3];
  const float* W2  = (const float*)d_in[4];
  const float* b2  = (const float*)d_in[5];
  const float* Wm1 = (const float*)d_in[6];
  const float* bm1 = (const float*)d_in[7];
  const float* Wm2 = (const float*)d_in[8];
  const float* bm2 = (const float*)d_in[9];
  float* out = (float*)d_out;

  char* ws = (char*)d_ws;
  size_t off = 0;
  auto alloc = [&](size_t bytes) -> void* {
    void* p = ws + off;
    off = (off + bytes + 511) & ~(size_t)511;
    return p;
  };
  int*      bucketCnt = (int*)     alloc((size_t)NBUCK * 4);
  unsigned* tmp       = (unsigned*)alloc((size_t)NBUCK * CAP_RAW * 4);  // 6.4 MB
  int*      colA      = (int*)     alloc((size_t)NBUCK * CAP_COL * 4);  // 9.6 MB
  int*      rowS      = (int*)     alloc((size_t)N_NODES * 4);
  int*      rowE      = (int*)     alloc((size_t)N_NODES * 4);
  float*    dinv      = (float*)   alloc((size_t)N_NODES * 4);
  __half*   g1        = (__half*)  alloc((size_t)(N_NODES + 1) * 64 * 2);  // +1 zero row
  float*    hA        = (float*)   alloc((size_t)N_NODES * 64 * 4);
  float*    hB        = (float*)   alloc((size_t)N_NODES * 64 * 4);
  (void)ws_size; (void)in_sizes; (void)n_in; (void)out_size;

  dim3 b256(256);
  int gGemm = (N_NODES + 127) / 128;
  int gAgg  = N_NODES / 8;  // 12500, exact
  int gBkt  = (N_EDGES + EPB_A - 1) / EPB_A;

  // preprocessing: 2-pass bucket sort -> padded CSR (shared by both convs)
  hipMemsetAsync(bucketCnt, 0, (size_t)NBUCK * 4, stream);
  bucket_kernel<<<gBkt, b256, 0, stream>>>(ei, bucketCnt, tmp);
  csr_kernel<<<NBUCK, dim3(512), 0, stream>>>(tmp, bucketCnt, colA, rowS, rowE, dinv);

  // conv1: g1 = (x@W1)*dinv (fp16); hB = dinv*(self+SUM)+b1 (fp32)
  gemm_g_kernel<<<gGemm, b256, 0, stream>>>(x, W1, dinv, g1, 0);
  aggregate_kernel<<<gAgg, b256, 0, stream>>>(g1, colA, rowS, rowE, dinv, b1, hB);

  // conv2: g1 = (relu(hB)@W2)*dinv (fp16); hB = dinv*(self+SUM)+b2 (fp32)
  gemm_g_kernel<<<gGemm, b256, 0, stream>>>(hB, W2, dinv, g1, 1);
  aggregate_kernel<<<gAgg, b256, 0, stream>>>(g1, colA, rowS, rowE, dinv, b2, hB);

  // MLP: hA = relu(hB@Wm1+bm1); out = hA@Wm2+bm2  (two single-phase GEMMs)
  gemm_kernel<64><<<gGemm, b256, 0, stream>>>(hB, Wm1, bm1, hA, N_NODES, 0, 1);
  gemm_kernel<40><<<gGemm, b256, 0, stream>>>(hA, Wm2, bm2, out, N_NODES, 0, 0);
}

// Round 4
// 249.015 us; speedup vs baseline: 4.3007x; 1.0129x over previous
//
#include <hip/hip_runtime.h>
#include <hip/hip_bf16.h>
#include <hip/hip_fp16.h>

// GCN: h1 = relu(GCNConv(x,W1,b1)); h2 = GCNConv(h1,W2,b2);
//      h3 = relu(h2@Wm1+bm1); out = h3@Wm2+bm2
// R2: CSR-by-dst gather-reduce replaced scatter atomics (10x write amp).
// R4: 2-pass XCD-local bucket sort. R5: dinv folded into GEMM epilogue.
// R6/R8 FAILED: multi-phase LDS GEMM fusion -> spills. R7: fp16 g-tables.
// R9: 2-node/wave aggregate, 8-deep (255.8us). R13 FAILED: 4-deep (263us).
// R14: cleanup (253.7us). R15 FAILED (1071us): scatter-side LDS agg -- 16x
//      fewer waves; binding resource is latency-hiding slack. R16 FAILED
//      (268.5us): perm pairing (pad gathers hit L1-hot zero row == cheap).
// R17 NEUTRAL (252.2us): depth 8->16. Pipeline saturates at 8; latency is
//      hidden. Lever is work structure, not concurrency.
// R18: fuse per-row 64x64 GEMMs into aggregate epilogues (VALU idle at 3%).
//      agg1: h1=dinv*(self+sum)+b1, relu, @W2 (LDS), *dinv, fp16 -> g2 table.
//      agg2: h2=dinv*(self+sum)+b2, @Wm1, +bm1, relu -> hA fp32.
//      Kills gemm_g2 + gemm64 dispatches and all hB traffic (~64MB).
//      Per-half-wave row staged in its own LDS slot (wave-synchronous, no
//      barrier); W 16KB LDS; 18KB/block keeps 8 blocks/CU.

namespace {

constexpr int N_NODES = 100000;
constexpr int N_EDGES = 1000000;
constexpr int NBUCK = (N_NODES + 511) / 512;  // 196 buckets of 512 nodes
constexpr int CAP_RAW = 8192;   // raw edges/bucket (mean 5120, sd ~71)
constexpr int CAP_COL = 12288;  // pad-16 edges/bucket (mean ~8400, sd ~80)
constexpr int EPB_A = 2048;     // edges per passA block

// passA: partition edges into NBUCK buckets by dst>>9. word=(src<<9)|(dst&511).
// Per-block int32/int64 detection: sample 512 odd words of own range (int64
// high halves are all 0; int32 node ids ~surely not).
__global__ __launch_bounds__(256) void bucket_kernel(const void* __restrict__ ei,
                                                     int* __restrict__ bucketCnt,
                                                     unsigned* __restrict__ tmp) {
  __shared__ int hist[NBUCK];
  __shared__ int basePB[NBUCK];
  __shared__ int cur[NBUCK];
  __shared__ int sflag;
  int t = threadIdx.x;
  if (t < NBUCK) { hist[t] = 0; cur[t] = 0; }
  if (t == 0) sflag = 0;
  __syncthreads();

  int e0 = blockIdx.x * EPB_A;
  const unsigned* w = (const unsigned*)ei;
  unsigned any = 0;
#pragma unroll
  for (int s = 0; s < 2; s++) {
    int e = e0 + s * 256 + t;
    if (e < N_EDGES) any |= w[2 * e + 1];
  }
  if (any) sflag = 1;  // benign race, all writers store 1
  __syncthreads();
  int is32 = sflag;

  unsigned wreg[8];
  int breg[8];
#pragma unroll
  for (int k = 0; k < 8; k++) {
    int e = e0 + k * 256 + t;
    breg[k] = -1;
    if (e < N_EDGES) {
      int s, d;
      if (is32) {
        const int* p = (const int*)ei;
        s = p[e]; d = p[N_EDGES + e];
      } else {
        const long long* p = (const long long*)ei;
        s = (int)p[e]; d = (int)p[N_EDGES + e];
      }
      wreg[k] = ((unsigned)s << 9) | (unsigned)(d & 511);
      breg[k] = d >> 9;
      atomicAdd(&hist[breg[k]], 1);
    }
  }
  __syncthreads();
  if (t < NBUCK) basePB[t] = hist[t] ? atomicAdd(&bucketCnt[t], hist[t]) : 0;
  __syncthreads();
#pragma unroll
  for (int k = 0; k < 8; k++) {
    if (breg[k] >= 0) {
      int r = atomicAdd(&cur[breg[k]], 1);
      tmp[(size_t)breg[k] * CAP_RAW + basePB[breg[k]] + r] = wreg[k];
    }
  }
}

// passB: one block per bucket. LDS counting sort; rows padded to mult 16 with
// sentinel N_NODES (zero row); emit row_start/row_end + dinv.
__global__ __launch_bounds__(512) void csr_kernel(const unsigned* __restrict__ tmp,
                                                  const int* __restrict__ bucketCnt,
                                                  int* __restrict__ col,
                                                  int* __restrict__ row_start,
                                                  int* __restrict__ row_end,
                                                  float* __restrict__ dinv) {
  __shared__ int sc[512];
  __shared__ int hist[512];
  __shared__ unsigned stage[CAP_RAW];
  int b = blockIdx.x, t = threadIdx.x;
  int myCnt = bucketCnt[b];
  int baseT = b * CAP_RAW;
  int baseC = b * CAP_COL;

  hist[t] = 0;
  __syncthreads();
  for (int i = t; i < myCnt; i += 512) {
    unsigned w = tmp[(size_t)baseT + i];
    stage[i] = w;
    atomicAdd(&hist[w & 511u], 1);
  }
  __syncthreads();

  int deg = hist[t];
  int pdeg = (deg + 15) & ~15;  // pad rows to mult 16 (R17: 16-deep pipeline)
  sc[t] = pdeg;
  __syncthreads();
#pragma unroll
  for (int off = 1; off < 512; off <<= 1) {
    int u = (t >= off) ? sc[t - off] : 0;
    __syncthreads();
    sc[t] += u;
    __syncthreads();
  }
  int pexcl = sc[t] - pdeg;
  int d = b * 512 + t;
  if (d < N_NODES) {
    row_start[d] = baseC + pexcl;
    row_end[d] = baseC + pexcl + pdeg;
    dinv[d] = rsqrtf((float)deg + 1.0f);
  }
  __syncthreads();
  hist[t] = pexcl;
  __syncthreads();
  for (int i = t; i < myCnt; i += 512) {
    unsigned w = stage[i];
    int pos = atomicAdd(&hist[w & 511u], 1);
    col[baseC + pos] = (int)(w >> 9);
  }
  for (int j = deg; j < pdeg; j++) col[baseC + pexcl + j] = N_NODES;
}

__device__ inline uint4 pack_half8(const float* v) {
  __half2 h0 = __floats2half2_rn(v[0], v[1]);
  __half2 h1 = __floats2half2_rn(v[2], v[3]);
  __half2 h2 = __floats2half2_rn(v[4], v[5]);
  __half2 h3 = __floats2half2_rn(v[6], v[7]);
  uint4 u;
  u.x = *(unsigned*)&h0; u.y = *(unsigned*)&h1;
  u.z = *(unsigned*)&h2; u.w = *(unsigned*)&h3;
  return u;
}

// g[r] = (op(A[r])@W) * dinv[r], fp16 out, zero pad row N_NODES.
// 128 rows/block, 256 thr, thread = 4 rows x 8 cols. W staged in LDS.
__global__ __launch_bounds__(256) void gemm_g_kernel(const float* __restrict__ A,
                                                     const float* __restrict__ W,
                                                     const float* __restrict__ dinv,
                                                     __half* __restrict__ g,
                                                     __half* __restrict__ gpad2,
                                                     int reluIn) {
  __shared__ float Ws[64 * 64];
  int t = threadIdx.x;
  if (blockIdx.x == 0 && t < 32) {
    ((float*)(g + (size_t)N_NODES * 64))[t] = 0.f;  // pad row (this table)
    if (gpad2) ((float*)(gpad2 + (size_t)N_NODES * 64))[t] = 0.f;  // pad row (agg1's output table)
  }
  for (int i = t; i < 64 * 64 / 4; i += 256) ((float4*)Ws)[i] = ((const float4*)W)[i];
  __syncthreads();

  int rg = t >> 3, cg = t & 7;
  int r0 = blockIdx.x * 128 + rg * 4;
  int c0 = cg * 8;

  float acc[4][8];
#pragma unroll
  for (int i = 0; i < 4; i++)
#pragma unroll
    for (int j = 0; j < 8; j++) acc[i][j] = 0.f;

  const float4* A4 = (const float4*)A;
  for (int kk = 0; kk < 16; kk++) {
    float4 a[4];
#pragma unroll
    for (int i = 0; i < 4; i++) {
      int r = r0 + i;
      float4 v = (r < N_NODES) ? A4[(size_t)r * 16 + kk] : make_float4(0.f, 0.f, 0.f, 0.f);
      if (reluIn) {
        v.x = fmaxf(v.x, 0.f); v.y = fmaxf(v.y, 0.f);
        v.z = fmaxf(v.z, 0.f); v.w = fmaxf(v.w, 0.f);
      }
      a[i] = v;
    }
#pragma unroll
    for (int q = 0; q < 4; q++) {
      int k = kk * 4 + q;
      float w[8];
#pragma unroll
      for (int j = 0; j < 2; j++) *(float4*)&w[4 * j] = *(const float4*)&Ws[k * 64 + c0 + 4 * j];
#pragma unroll
      for (int i = 0; i < 4; i++) {
        float av = q == 0 ? a[i].x : q == 1 ? a[i].y : q == 2 ? a[i].z : a[i].w;
#pragma unroll
        for (int j = 0; j < 8; j++) acc[i][j] = fmaf(av, w[j], acc[i][j]);
      }
    }
  }
#pragma unroll
  for (int i = 0; i < 4; i++) {
    int r = r0 + i;
    if (r < N_NODES) {
      float s = dinv[r];
#pragma unroll
      for (int j = 0; j < 8; j++) acc[i][j] *= s;
      *(uint4*)(g + (size_t)r * 64 + c0) = pack_half8(acc[i]);
    }
  }
}

// Fused gather-aggregate + per-row 64x64 GEMM epilogue (R18).
// Gather phase identical to R17 (2 nodes/wave, 16-deep pipeline, sentinel pad
// rows). Epilogue: half-wave's completed row h = dinv*(self+sum)+bconv is
// staged in its own LDS slot (wave-synchronous, no barrier needed), then each
// lane computes output feats {2*sub, 2*sub+1} = h @ W (W staged in LDS, 2-way
// bank stride = free; h reads are broadcast = free).
// MODE 1 (conv1 -> conv2 g-table): relu(h) before GEMM, *dinv after, fp16 out.
// MODE 2 (conv2 -> MLP hidden):    no pre-relu, +bpost then relu, fp32 out.
template <int MODE>
__global__ __launch_bounds__(256) void agg_fused(const __half* __restrict__ g,
                                                 const int* __restrict__ col,
                                                 const int* __restrict__ row_start,
                                                 const int* __restrict__ row_end,
                                                 const float* __restrict__ dinv,
                                                 const float* __restrict__ bconv,
                                                 const float* __restrict__ W,
                                                 const float* __restrict__ bpost,
                                                 void* __restrict__ outp) {
  __shared__ float Ws[64 * 64];   // 16 KB
  __shared__ float rows[8][64];   // 2 KB, one row slot per half-wave
  int t = threadIdx.x;
  for (int i = t; i < 64 * 64 / 4; i += 256) ((float4*)Ws)[i] = ((const float4*)W)[i];
  __syncthreads();

  int wave = t >> 6;
  int lane = t & 63;
  int half = lane >> 5;
  int sub = lane & 31;
  int slot = t >> 5;  // half-wave id 0..7
  int d = blockIdx.x * 8 + wave * 2 + half;

  const __half2* g2 = (const __half2*)g;
  int e0 = row_start[d];
  int len = row_end[d] - e0;

  float2 a0 = __half22float2(g2[(size_t)d * 32 + sub]);  // self (dinv in g)
  float2 a1 = {0.f, 0.f}, a2 = {0.f, 0.f}, a3 = {0.f, 0.f};
  float2 a4 = {0.f, 0.f}, a5 = {0.f, 0.f}, a6 = {0.f, 0.f}, a7 = {0.f, 0.f};

  for (int i = 0; i < len; i += 16) {  // per-half-wave trip count (exec-mask divergence)
    int4 ca = *(const int4*)(col + e0 + i);
    int4 cb = *(const int4*)(col + e0 + i + 4);
    int4 cc = *(const int4*)(col + e0 + i + 8);
    int4 cd = *(const int4*)(col + e0 + i + 12);
    float2 h0 = __half22float2(g2[(size_t)ca.x * 32 + sub]);
    float2 h1 = __half22float2(g2[(size_t)ca.y * 32 + sub]);
    float2 h2 = __half22float2(g2[(size_t)ca.z * 32 + sub]);
    float2 h3 = __half22float2(g2[(size_t)ca.w * 32 + sub]);
    float2 h4 = __half22float2(g2[(size_t)cb.x * 32 + sub]);
    float2 h5 = __half22float2(g2[(size_t)cb.y * 32 + sub]);
    float2 h6 = __half22float2(g2[(size_t)cb.z * 32 + sub]);
    float2 h7 = __half22float2(g2[(size_t)cb.w * 32 + sub]);
    float2 h8 = __half22float2(g2[(size_t)cc.x * 32 + sub]);
    float2 h9 = __half22float2(g2[(size_t)cc.y * 32 + sub]);
    float2 hA = __half22float2(g2[(size_t)cc.z * 32 + sub]);
    float2 hB = __half22float2(g2[(size_t)cc.w * 32 + sub]);
    float2 hC = __half22float2(g2[(size_t)cd.x * 32 + sub]);
    float2 hD = __half22float2(g2[(size_t)cd.y * 32 + sub]);
    float2 hE = __half22float2(g2[(size_t)cd.z * 32 + sub]);
    float2 hF = __half22float2(g2[(size_t)cd.w * 32 + sub]);
    a0.x += h0.x; a0.y += h0.y; a1.x += h1.x; a1.y += h1.y;
    a2.x += h2.x; a2.y += h2.y; a3.x += h3.x; a3.y += h3.y;
    a4.x += h4.x; a4.y += h4.y; a5.x += h5.x; a5.y += h5.y;
    a6.x += h6.x; a6.y += h6.y; a7.x += h7.x; a7.y += h7.y;
    a0.x += h8.x; a0.y += h8.y; a1.x += h9.x; a1.y += h9.y;
    a2.x += hA.x; a2.y += hA.y; a3.x += hB.x; a3.y += hB.y;
    a4.x += hC.x; a4.y += hC.y; a5.x += hD.x; a5.y += hD.y;
    a6.x += hE.x; a6.y += hE.y; a7.x += hF.x; a7.y += hF.y;
  }
  float rx = ((a0.x + a1.x) + (a2.x + a3.x)) + ((a4.x + a5.x) + (a6.x + a7.x));
  float ry = ((a0.y + a1.y) + (a2.y + a3.y)) + ((a4.y + a5.y) + (a6.y + a7.y));
  float dv = dinv[d];
  float2 bv = ((const float2*)bconv)[sub];
  float hx = fmaf(rx, dv, bv.x);
  float hy = fmaf(ry, dv, bv.y);
  if (MODE == 1) { hx = fmaxf(hx, 0.f); hy = fmaxf(hy, 0.f); }

  // stage row in this half-wave's slot; wave-synchronous (single-instruction
  // write covers all lanes, subsequent reads ordered by lgkmcnt)
  *(float2*)&rows[slot][2 * sub] = make_float2(hx, hy);

  float o0 = 0.f, o1 = 0.f;
#pragma unroll 8
  for (int ks = 0; ks < 32; ks++) {
    float2 hv = *(const float2*)&rows[slot][2 * ks];           // broadcast
    float2 w0 = *(const float2*)&Ws[(2 * ks) * 64 + 2 * sub];  // 2-way bank
    float2 w1 = *(const float2*)&Ws[(2 * ks + 1) * 64 + 2 * sub];
    o0 = fmaf(hv.x, w0.x, o0);
    o0 = fmaf(hv.y, w1.x, o0);
    o1 = fmaf(hv.x, w0.y, o1);
    o1 = fmaf(hv.y, w1.y, o1);
  }

  if (MODE == 1) {
    o0 *= dv; o1 *= dv;
    __half2 hh = __floats2half2_rn(o0, o1);
    ((__half2*)outp)[(size_t)d * 32 + sub] = hh;
  } else {
    float2 bp = ((const float2*)bpost)[sub];
    float2 o;
    o.x = fmaxf(o0 + bp.x, 0.f);
    o.y = fmaxf(o1 + bp.y, 0.f);
    ((float2*)outp)[(size_t)d * 32 + sub] = o;
  }
}

// fp32 GEMM for the MLP tail: C[n,F] = op(A[n,64])@W[64,F] (+bias)(relu).
// Single-phase only (see R6/R8 spill rule).
template <int F>
__global__ __launch_bounds__(256) void gemm_kernel(const float* __restrict__ A, const float* __restrict__ W,
                                                   const float* __restrict__ bias, float* __restrict__ C,
                                                   int n, int reluIn, int reluOut) {
  constexpr int CPT = F / 8;
  __shared__ float Ws[64 * F];
  int t = threadIdx.x;
  for (int i = t; i < 64 * F / 4; i += 256) ((float4*)Ws)[i] = ((const float4*)W)[i];
  __syncthreads();

  int rg = t >> 3, cg = t & 7;
  int r0 = blockIdx.x * 128 + rg * 4;
  int c0 = cg * CPT;

  float acc[4][CPT];
#pragma unroll
  for (int i = 0; i < 4; i++)
#pragma unroll
    for (int j = 0; j < CPT; j++) acc[i][j] = 0.f;

  const float4* A4 = (const float4*)A;
  for (int kk = 0; kk < 16; kk++) {
    float4 a[4];
#pragma unroll
    for (int i = 0; i < 4; i++) {
      int r = r0 + i;
      float4 v = (r < n) ? A4[(size_t)r * 16 + kk] : make_float4(0.f, 0.f, 0.f, 0.f);
      if (reluIn) {
        v.x = fmaxf(v.x, 0.f); v.y = fmaxf(v.y, 0.f);
        v.z = fmaxf(v.z, 0.f); v.w = fmaxf(v.w, 0.f);
      }
      a[i] = v;
    }
#pragma unroll
    for (int q = 0; q < 4; q++) {
      int k = kk * 4 + q;
      float w[CPT];
      if constexpr (CPT % 4 == 0) {
#pragma unroll
        for (int j = 0; j < CPT / 4; j++)
          *(float4*)&w[4 * j] = *(const float4*)&Ws[k * F + c0 + 4 * j];  // ds_read_b128
      } else {
#pragma unroll
        for (int j = 0; j < CPT; j++) w[j] = Ws[k * F + c0 + j];
      }
#pragma unroll
      for (int i = 0; i < 4; i++) {
        float av = q == 0 ? a[i].x : q == 1 ? a[i].y : q == 2 ? a[i].z : a[i].w;
#pragma unroll
        for (int j = 0; j < CPT; j++) acc[i][j] = fmaf(av, w[j], acc[i][j]);
      }
    }
  }

  float bv[CPT];
#pragma unroll
  for (int j = 0; j < CPT; j++) bv[j] = bias ? bias[c0 + j] : 0.f;
#pragma unroll
  for (int i = 0; i < 4; i++) {
    int r = r0 + i;
    if (r < n) {
      float* crow = C + (size_t)r * F + c0;
#pragma unroll
      for (int j = 0; j < CPT; j++) {
        float v = acc[i][j] + bv[j];
        if (reluOut) v = fmaxf(v, 0.f);
        crow[j] = v;
      }
    }
  }
}

}  // namespace

extern "C" void kernel_launch(void* const* d_in, const int* in_sizes, int n_in,
                              void* d_out, int out_size, void* d_ws, size_t ws_size,
                              hipStream_t stream) {
  const float* x   = (const float*)d_in[0];
  const void*  ei  = d_in[1];
  const float* W1  = (const float*)d_in[2];
  const float* b1  = (const float*)d_in[3];
  const float* W2  = (const float*)d_in[4];
  const float* b2  = (const float*)d_in[5];
  const float* Wm1 = (const float*)d_in[6];
  const float* bm1 = (const float*)d_in[7];
  const float* Wm2 = (const float*)d_in[8];
  const float* bm2 = (const float*)d_in[9];
  float* out = (float*)d_out;

  char* ws = (char*)d_ws;
  size_t off = 0;
  auto alloc = [&](size_t bytes) -> void* {
    void* p = ws + off;
    off = (off + bytes + 511) & ~(size_t)511;
    return p;
  };
  int*      bucketCnt = (int*)     alloc((size_t)NBUCK * 4);
  unsigned* tmp       = (unsigned*)alloc((size_t)NBUCK * CAP_RAW * 4);  // 6.4 MB
  int*      colA      = (int*)     alloc((size_t)NBUCK * CAP_COL * 4);  // 9.6 MB
  int*      rowS      = (int*)     alloc((size_t)N_NODES * 4);
  int*      rowE      = (int*)     alloc((size_t)N_NODES * 4);
  float*    dinv      = (float*)   alloc((size_t)N_NODES * 4);
  __half*   g1        = (__half*)  alloc((size_t)(N_NODES + 1) * 64 * 2);  // +1 zero row
  __half*   gB        = (__half*)  alloc((size_t)(N_NODES + 1) * 64 * 2);  // conv2 table
  float*    hA        = (float*)   alloc((size_t)N_NODES * 64 * 4);
  (void)ws_size; (void)in_sizes; (void)n_in; (void)out_size;

  dim3 b256(256);
  int gGemm = (N_NODES + 127) / 128;
  int gAgg  = N_NODES / 8;  // 12500, exact
  int gBkt  = (N_EDGES + EPB_A - 1) / EPB_A;

  // preprocessing: 2-pass bucket sort -> padded CSR (shared by both convs)
  hipMemsetAsync(bucketCnt, 0, (size_t)NBUCK * 4, stream);
  bucket_kernel<<<gBkt, b256, 0, stream>>>(ei, bucketCnt, tmp);
  csr_kernel<<<NBUCK, dim3(512), 0, stream>>>(tmp, bucketCnt, colA, rowS, rowE, dinv);

  // conv1 tables: g1 = (x@W1)*dinv (fp16); also zeroes both pad rows
  gemm_g_kernel<<<gGemm, b256, 0, stream>>>(x, W1, dinv, g1, gB, 0);

  // conv1 aggregate + fused conv2 gemm: gB = (relu(dinv*(self+sum)+b1)@W2)*dinv
  agg_fused<1><<<gAgg, b256, 0, stream>>>(g1, colA, rowS, rowE, dinv, b1, W2, nullptr, gB);

  // conv2 aggregate + fused MLP-1: hA = relu((dinv*(self+sum)+b2)@Wm1 + bm1)
  agg_fused<2><<<gAgg, b256, 0, stream>>>(gB, colA, rowS, rowE, dinv, b2, Wm1, bm1, hA);

  // MLP tail: out = hA@Wm2+bm2
  gemm_kernel<40><<<gGemm, b256, 0, stream>>>(hA, Wm2, bm2, out, N_NODES, 0, 0);
}